// Round 8
// baseline (473.695 us; speedup 1.0000x reference)
//
#include <hip/hip_runtime.h>
#include <hip/hip_bf16.h>
#include <stdint.h>
#include <type_traits>

// ---------------------------------------------------------------------------
// MultiExpertMoELayer: opcode-routed 2-stage FFN chain.
//   op = argmax(x[0,0,0:8]);  for e in 0..1: x = gelu(x@W1[op,e]+b1)@W2[op,e]+b2
// Round 8: FLAT-B GEMM (AITER flatmm structure).
//   R7 post-mortem arithmetic: with A+B both in LDS, per-CU LDS traffic
//   (2304 cyc reads + 512 DMA writes) >= MFMA floor (2483 cyc) -> LDS-bound,
//   ~880 TF ceiling regardless of schedule (R2-R7 all 338-393us).
//   -> prep packs B into MFMA-frag order [K/64][N/16][ks][lane][8]; GEMM
//      loads B-frags as coalesced 1KB global_load_dwordx4 directly to VGPRs
//      (B panel L2/L3-resident). LDS carries A only: 1792 cyc < 2483 MFMA.
//   B-regs double-buffered via 2x-unrolled K-loop (static parity, rule 20);
//   plain C loads for B (compiler inserts counted waits); "" memory fences
//   pin stage_A -> load_B issue order so vmcnt(SA+16) drains exactly A(t).
// Canary: absmax must stay exactly 0.01171875 (same values, same DAG).
// ---------------------------------------------------------------------------

typedef __attribute__((ext_vector_type(8))) short short8;   // 8 x bf16 (4 VGPR)
typedef __attribute__((ext_vector_type(4))) float f32x4;    // MFMA accum

#define LGKM0  asm volatile("s_waitcnt lgkmcnt(0)" ::: "memory")
#define SBAR   __builtin_amdgcn_s_barrier()
#define CFENCE asm volatile("" ::: "memory")

template<int VM> __device__ __forceinline__ void wait_vm() {
  if constexpr (VM == 20)      asm volatile("s_waitcnt vmcnt(20)" ::: "memory");
  else if constexpr (VM == 18) asm volatile("s_waitcnt vmcnt(18)" ::: "memory");
  else if constexpr (VM == 8)  asm volatile("s_waitcnt vmcnt(8)"  ::: "memory");
  else                         asm volatile("s_waitcnt vmcnt(0)"  ::: "memory");
}

__device__ __forceinline__ unsigned short f2bf(float f) {
  union { float f; uint32_t u; } v; v.f = f;
  return (unsigned short)((v.u + 0x7fffu + ((v.u >> 16) & 1u)) >> 16);  // RNE
}

// jax.nn.gelu(approximate=True): 0.5x(1+tanh(sqrt(2/pi)(x+0.044715x^3)))
__device__ __forceinline__ float gelu_tanh(float x) {
  float u = 0.7978845608028654f * (x + 0.044715f * x * x * x);
  float e = __expf(2.0f * u);
  float t = 1.0f - 2.0f / (e + 1.0f);   // tanh(u), safe at +/-inf
  return 0.5f * x * (1.0f + t);
}

__device__ __forceinline__ void gload_lds16(const void* g, void* l) {
  __builtin_amdgcn_global_load_lds(
      (const __attribute__((address_space(1))) void*)g,
      (__attribute__((address_space(3))) void*)l, 16, 0, 0);
}

// op = argmax(x[0,0,0:8]), first-max wins (matches jnp.argmax).
__device__ __forceinline__ int compute_op(const float* __restrict__ x) {
  int best = 0; float bv = x[0];
#pragma unroll
  for (int i = 1; i < 8; ++i) { float v = x[i]; if (v > bv) { bv = v; best = i; } }
  return best;
}

// --------------------------- fused prep kernel ------------------------------
// blocks [0, 4096)        : x fp32 -> bf16 (8 elems/thread)
// blocks [4096, 8192)     : 4 pack jobs of 1024 blocks each:
//   W[op,e] [K][N] fp32 -> Bpack bf16 [K/64][N/16][2(ks)][64(lane)][8(k-elems)]
//   where frag chunk (kt,nf,ks,lane): n = nf*16 + (lane&15),
//                                     k = kt*64 + ks*32 + (lane>>4)*8 + e.
__global__ __launch_bounds__(256) void prep_kernel(
    const float* __restrict__ x, const float* __restrict__ W1,
    const float* __restrict__ W2,
    unsigned short* __restrict__ xb, unsigned short* __restrict__ w1p,
    unsigned short* __restrict__ w2p) {
  __shared__ float tile[64][65];
  const int bid = blockIdx.x;
  const int t = threadIdx.x;
  if (bid < 4096) {
    const int i = bid * 256 + t;
    const float4* xv = (const float4*)x;
    float4 v0 = xv[i * 2], v1 = xv[i * 2 + 1];
    ushort4 o0, o1;
    o0.x = f2bf(v0.x); o0.y = f2bf(v0.y); o0.z = f2bf(v0.z); o0.w = f2bf(v0.w);
    o1.x = f2bf(v1.x); o1.y = f2bf(v1.y); o1.z = f2bf(v1.z); o1.w = f2bf(v1.w);
    ((ushort4*)xb)[i * 2] = o0; ((ushort4*)xb)[i * 2 + 1] = o1;
    return;
  }
  const int op = compute_op(x);
  const int j = bid - 4096;
  const int job = j >> 10, w = j & 1023;
  const int e = job & 1;
  const bool isW1 = (job < 2);
  const int K = isW1 ? 1024 : 4096;        // W is [K][N]
  const int N = isW1 ? 4096 : 1024;
  const float* W = (isW1 ? W1 : W2) + ((size_t)op * 2 + (size_t)e) * (size_t)K * N;
  unsigned short* dst0 = (isW1 ? w1p : w2p) + (size_t)e * 4096 * 1024;
  const int tc = w % (N >> 6), tr = w / (N >> 6);   // tr: k-tile, tc: n-tile
  {
    const int r  = t >> 2;                  // k within tile
    const int c0 = (t & 3) * 16;            // n within tile
    const float* src = W + (size_t)(tr * 64 + r) * N + tc * 64 + c0;
#pragma unroll
    for (int jj = 0; jj < 16; jj += 4) {
      float4 v = *(const float4*)(src + jj);
      tile[r][c0 + jj]     = v.x;
      tile[r][c0 + jj + 1] = v.y;
      tile[r][c0 + jj + 2] = v.z;
      tile[r][c0 + jj + 3] = v.w;
    }
  }
  __syncthreads();
#pragma unroll
  for (int rep = 0; rep < 2; ++rep) {
    const int id2 = rep * 256 + t;          // 512 chunks per 64x64 tile
    const int nf_l = id2 >> 7;              // 0..3
    const int ks   = (id2 >> 6) & 1;
    const int lane = id2 & 63;
    const int n_l  = nf_l * 16 + (lane & 15);
    const int k_l  = ks * 32 + (lane >> 4) * 8;
    short8 o;
#pragma unroll
    for (int ee = 0; ee < 8; ++ee) o[ee] = (short)f2bf(tile[k_l + ee][n_l]);
    const size_t chunk = ((size_t)(tr * (N >> 4) + tc * 4 + nf_l) * 2 + ks) * 64 + lane;
    *(short8*)(dst0 + chunk * 8) = o;
  }
}

// --------------------------- flat-B GEMM ------------------------------------
// C = A @ B + bias [,gelu].  A: [M][K] bf16 via LDS (gload_lds + XOR swizzle),
// B: frag-packed bf16 loaded straight to VGPRs (no LDS).
// BN=256 fixed, 8 waves 2M x 4N; per-wave (BM/2) x 64, NR=4.

template<int BM>
__device__ __forceinline__ void stage_A(
    const unsigned short* __restrict__ Ab, int K, int kb,
    short* __restrict__ dst, int tid) {
#pragma unroll
  for (int j = 0; j < BM / 64; ++j) {
    const int ci = j * 512 + tid;
    const int row = ci >> 3;
    const int gc = (ci & 7) ^ (row & 7);
    gload_lds16(Ab + (size_t)row * K + kb + gc * 8, dst + ci * 8);
  }
}

template<int BM, bool SLOW_BM, bool GELU, typename OUT_T>
__global__ __launch_bounds__(512, 2) void gemm_flat(
    const unsigned short* __restrict__ A,
    const unsigned short* __restrict__ Bp,   // frag-packed
    const float* __restrict__ x_op,
    const float* __restrict__ bias_base,     // [8][2][N]
    int expert, OUT_T* __restrict__ Cout, int M, int N, int K)
{
  constexpr int BN = 256, NR = 4;
  constexpr int MR = BM / 32;             // 16-row frags per wave (8 or 4)
  constexpr int SA = BM / 64;             // A stage instrs per K-tile
  constexpr int BUF = BM * 64;            // shorts per A double-buffer half
  __shared__ short smem[2 * BUF];

  const int tid  = threadIdx.x;
  const int wid  = tid >> 6, lane = tid & 63;
  const int wm   = wid >> 2, wn = wid & 3;
  const int lq   = lane >> 4, lr = lane & 15;

  const int nwg = gridDim.x;
  const int id  = blockIdx.x;
  const int s   = (id & 7) * (nwg >> 3) + (id >> 3);
  int bm, bn;
  if constexpr (SLOW_BM) { const int nbn = N / BN; bm = s / nbn; bn = s % nbn; }
  else                   { const int nbm = M / BM; bn = s / nbm; bm = s % nbm; }

  const unsigned short* Ab = A + (size_t)bm * BM * K;
  const short8* Bq = (const short8*)Bp;
  const int nf0 = bn * (BN / 16) + wn * NR;
  const int nf_stride = N >> 4;

  f32x4 acc[MR][NR] = {};
  short8 bregA[NR][2], bregB[NR][2];

  auto load_B = [&](int kt, short8 (&br)[NR][2]) {
#pragma unroll
    for (int n = 0; n < NR; ++n)
#pragma unroll
      for (int ks = 0; ks < 2; ++ks)
        br[n][ks] = Bq[((size_t)(kt * nf_stride + nf0 + n) * 2 + ks) * 64 + lane];
  };

  auto compute = [&](const char* cA, const short8 (&bc)[NR][2]) {
#pragma unroll
    for (int ks = 0; ks < 2; ++ks)
#pragma unroll
      for (int mh = 0; mh < 2; ++mh) {
        short8 af[MR / 2];
#pragma unroll
        for (int mm = 0; mm < MR / 2; ++mm) {
          const int ra = wm * (BM / 2) + (mh * (MR / 2) + mm) * 16 + lr;
          const int ch = ((ks << 2) | lq) ^ (ra & 7);
          af[mm] = *(const short8*)(cA + ra * 128 + ch * 16);
        }
#pragma unroll
        for (int mm = 0; mm < MR / 2; ++mm)
#pragma unroll
          for (int n = 0; n < NR; ++n)
            acc[mh * (MR / 2) + mm][n] = __builtin_amdgcn_mfma_f32_16x16x32_bf16(
                af[mm], bc[n][ks], acc[mh * (MR / 2) + mm][n], 0, 0, 0);
      }
  };

  // prologue: A(0) staged, B(0) loaded (order pinned: A first -> vmcnt math)
  stage_A<BM>(Ab, K, 0, smem, tid);
  CFENCE;
  load_B(0, bregA);
  CFENCE;

  const int nkt = K / 64;                 // 16 or 64: always even
  for (int t = 0; t < nkt; t += 2) {
    { // even tile: consume bregA from buf0
      if (t + 1 < nkt) {
        stage_A<BM>(Ab, K, (t + 1) * 64, smem + BUF, tid);
        CFENCE;
        load_B(t + 1, bregB);
        CFENCE;
        wait_vm<SA + 16>();   // drains exactly A(t); t+1 stays in flight (T4)
      } else wait_vm<8>();
      SBAR;
      compute((const char*)smem, bregA);
      LGKM0; SBAR;
    }
    { // odd tile: consume bregB from buf1 (t+1 < nkt since nkt even)
      if (t + 2 < nkt) {
        stage_A<BM>(Ab, K, (t + 2) * 64, smem, tid);
        CFENCE;
        load_B(t + 2, bregA);
        CFENCE;
        wait_vm<SA + 16>();
      } else wait_vm<8>();
      SBAR;
      compute((const char*)(smem + BUF), bregB);
      LGKM0; SBAR;
    }
  }

  // Epilogue: C/D layout col=lane&15, row=(lane>>4)*4+reg [m89-verified]
  const int op = compute_op(x_op);
  const float* bias = bias_base + ((size_t)op * 2 + (size_t)expert) * (size_t)N;
#pragma unroll
  for (int f = 0; f < MR; ++f) {
    const int grow0 = bm * BM + wm * (BM / 2) + f * 16 + lq * 4;
#pragma unroll
    for (int n = 0; n < NR; ++n) {
      const int gcol = bn * BN + wn * 64 + n * 16 + lr;
      const float bv = bias[gcol];
#pragma unroll
      for (int r = 0; r < 4; ++r) {
        float v = acc[f][n][r] + bv;
        if constexpr (GELU) v = gelu_tanh(v);
        const size_t off = (size_t)(grow0 + r) * N + gcol;
        if constexpr (std::is_same<OUT_T, float>::value) Cout[off] = v;
        else Cout[off] = f2bf(v);
      }
    }
  }
}

// --------------------------- launcher ---------------------------------------
extern "C" void kernel_launch(void* const* d_in, const int* in_sizes, int n_in,
                              void* d_out, int out_size, void* d_ws, size_t ws_size,
                              hipStream_t stream) {
  const float* x  = (const float*)d_in[0];
  const float* W1 = (const float*)d_in[1];   // [8][2][1024][4096]
  const float* b1 = (const float*)d_in[2];   // [8][2][4096]
  const float* W2 = (const float*)d_in[3];   // [8][2][4096][1024]
  const float* b2 = (const float*)d_in[4];   // [8][2][1024]
  float* out = (float*)d_out;

  const int D = 1024, F = 4096, M = 8192;    // M = B*S = 4*2048

  // ws layout: [xb 16.8MB][w1p 16.8MB][w2p 16.8MB][h 67.1MB]
  char* ws = (char*)d_ws;
  unsigned short* xb  = (unsigned short*)ws;
  unsigned short* w1p = (unsigned short*)(ws + (size_t)M * D * 2);
  unsigned short* w2p = (unsigned short*)(ws + (size_t)M * D * 2 + (size_t)2 * D * F * 2);
  unsigned short* h   = (unsigned short*)(ws + (size_t)M * D * 2 + (size_t)4 * D * F * 2);
  unsigned short* x1b = (unsigned short*)d_out;  // stage-0 output parked in d_out

  prep_kernel<<<4096 + 4 * 1024, 256, 0, stream>>>(x, W1, W2, xb, w1p, w2p);

  // GEMM1: M=8192,N=4096,K=1024  BM=256, grid 512, bm-slow chunks
  // GEMM2: M=8192,N=1024,K=4096  BM=128, grid 256, bn-slow chunks
  // expert 0
  gemm_flat<256, true,  true,  unsigned short><<<(M/256)*(F/256), 512, 0, stream>>>(xb,  w1p,                 x, b1, 0, h,   M, F, D);
  gemm_flat<128, false, false, unsigned short><<<(M/128)*(D/256), 512, 0, stream>>>(h,   w2p,                 x, b2, 0, x1b, M, D, F);
  // expert 1
  gemm_flat<256, true,  true,  unsigned short><<<(M/256)*(F/256), 512, 0, stream>>>(x1b, w1p + (size_t)F * D, x, b1, 1, h,   M, F, D);
  gemm_flat<128, false, false, float         ><<<(M/128)*(D/256), 512, 0, stream>>>(h,   w2p + (size_t)D * F, x, b2, 1, out, M, D, F);
}

// Round 9
// 406.207 us; speedup vs baseline: 1.1661x; 1.1661x over previous
//
#include <hip/hip_runtime.h>
#include <hip/hip_bf16.h>
#include <stdint.h>
#include <type_traits>

// ---------------------------------------------------------------------------
// MultiExpertMoELayer: opcode-routed 2-stage FFN chain.
//   op = argmax(x[0,0,0:8]);  for e in 0..1: x = gelu(x@W1[op,e]+b1)@W2[op,e]+b2
// Round 9: flat-B GEMM, SPILL FIX.
//   R8 counters: VGPR_Count=128, WRITE 183MB (116MB scratch!), MfmaUtil 13.8%
//   -> register spill from acc128 + B-double-buffer 64 + dual addressing.
//   Fixes: (1) single-buffered B regs (32 not 64); (2) GEMM1 keeps BM=256
//   (acc128+breg32+af16+addr~30 ~= 206 <= 256 budget), GEMM2 BM=128 (~140);
//   (3) GEMM1 bn-slow XCD chunks (B-panels 1MB L2-resident; A via DMA which
//   tolerates latency); (4) vmcnt re-derived: issue B(t),A(t+1) atop A(t),
//   wait vmcnt(8+SA) drains exactly A(t) (T4: t+1 + B stay in flight).
// Canary: absmax must stay exactly 0.01171875 (same values, same DAG).
// ---------------------------------------------------------------------------

typedef __attribute__((ext_vector_type(8))) short short8;   // 8 x bf16 (4 VGPR)
typedef __attribute__((ext_vector_type(4))) float f32x4;    // MFMA accum

#define LGKM0  asm volatile("s_waitcnt lgkmcnt(0)" ::: "memory")
#define SBAR   __builtin_amdgcn_s_barrier()

template<int VM> __device__ __forceinline__ void wait_vm() {
  if constexpr (VM == 12)      asm volatile("s_waitcnt vmcnt(12)" ::: "memory");
  else if constexpr (VM == 10) asm volatile("s_waitcnt vmcnt(10)" ::: "memory");
  else if constexpr (VM == 8)  asm volatile("s_waitcnt vmcnt(8)"  ::: "memory");
  else                         asm volatile("s_waitcnt vmcnt(0)"  ::: "memory");
}

__device__ __forceinline__ unsigned short f2bf(float f) {
  union { float f; uint32_t u; } v; v.f = f;
  return (unsigned short)((v.u + 0x7fffu + ((v.u >> 16) & 1u)) >> 16);  // RNE
}

// jax.nn.gelu(approximate=True): 0.5x(1+tanh(sqrt(2/pi)(x+0.044715x^3)))
__device__ __forceinline__ float gelu_tanh(float x) {
  float u = 0.7978845608028654f * (x + 0.044715f * x * x * x);
  float e = __expf(2.0f * u);
  float t = 1.0f - 2.0f / (e + 1.0f);   // tanh(u), safe at +/-inf
  return 0.5f * x * (1.0f + t);
}

__device__ __forceinline__ void gload_lds16(const void* g, void* l) {
  __builtin_amdgcn_global_load_lds(
      (const __attribute__((address_space(1))) void*)g,
      (__attribute__((address_space(3))) void*)l, 16, 0, 0);
}

// op = argmax(x[0,0,0:8]), first-max wins (matches jnp.argmax).
__device__ __forceinline__ int compute_op(const float* __restrict__ x) {
  int best = 0; float bv = x[0];
#pragma unroll
  for (int i = 1; i < 8; ++i) { float v = x[i]; if (v > bv) { bv = v; best = i; } }
  return best;
}

// --------------------------- fused prep kernel ------------------------------
// blocks [0, 4096)   : x fp32 -> bf16 (8 elems/thread)
// blocks [4096, 8192): 4 pack jobs of 1024 blocks each:
//   W[op,e] [K][N] fp32 -> Bpack bf16 [K/64][N/16][2(ks)][64(lane)][8(k)]
//   frag chunk (kt,nf,ks,lane): n = nf*16 + (lane&15),
//                               k = kt*64 + ks*32 + (lane>>4)*8 + e.
__global__ __launch_bounds__(256) void prep_kernel(
    const float* __restrict__ x, const float* __restrict__ W1,
    const float* __restrict__ W2,
    unsigned short* __restrict__ xb, unsigned short* __restrict__ w1p,
    unsigned short* __restrict__ w2p) {
  __shared__ float tile[64][65];
  const int bid = blockIdx.x;
  const int t = threadIdx.x;
  if (bid < 4096) {
    const int i = bid * 256 + t;
    const float4* xv = (const float4*)x;
    float4 v0 = xv[i * 2], v1 = xv[i * 2 + 1];
    ushort4 o0, o1;
    o0.x = f2bf(v0.x); o0.y = f2bf(v0.y); o0.z = f2bf(v0.z); o0.w = f2bf(v0.w);
    o1.x = f2bf(v1.x); o1.y = f2bf(v1.y); o1.z = f2bf(v1.z); o1.w = f2bf(v1.w);
    ((ushort4*)xb)[i * 2] = o0; ((ushort4*)xb)[i * 2 + 1] = o1;
    return;
  }
  const int op = compute_op(x);
  const int j = bid - 4096;
  const int job = j >> 10, w = j & 1023;
  const int e = job & 1;
  const bool isW1 = (job < 2);
  const int K = isW1 ? 1024 : 4096;        // W is [K][N]
  const int N = isW1 ? 4096 : 1024;
  const float* W = (isW1 ? W1 : W2) + ((size_t)op * 2 + (size_t)e) * (size_t)K * N;
  unsigned short* dst0 = (isW1 ? w1p : w2p) + (size_t)e * 4096 * 1024;
  const int tc = w % (N >> 6), tr = w / (N >> 6);   // tr: k-tile, tc: n-tile
  {
    const int r  = t >> 2;                  // k within tile
    const int c0 = (t & 3) * 16;            // n within tile
    const float* src = W + (size_t)(tr * 64 + r) * N + tc * 64 + c0;
#pragma unroll
    for (int jj = 0; jj < 16; jj += 4) {
      float4 v = *(const float4*)(src + jj);
      tile[r][c0 + jj]     = v.x;
      tile[r][c0 + jj + 1] = v.y;
      tile[r][c0 + jj + 2] = v.z;
      tile[r][c0 + jj + 3] = v.w;
    }
  }
  __syncthreads();
#pragma unroll
  for (int rep = 0; rep < 2; ++rep) {
    const int id2 = rep * 256 + t;          // 512 chunks per 64x64 tile
    const int nf_l = id2 >> 7;              // 0..3
    const int ks   = (id2 >> 6) & 1;
    const int lane = id2 & 63;
    const int n_l  = nf_l * 16 + (lane & 15);
    const int k_l  = ks * 32 + (lane >> 4) * 8;
    short8 o;
#pragma unroll
    for (int ee = 0; ee < 8; ++ee) o[ee] = (short)f2bf(tile[k_l + ee][n_l]);
    const size_t chunk = ((size_t)(tr * (N >> 4) + tc * 4 + nf_l) * 2 + ks) * 64 + lane;
    *(short8*)(dst0 + chunk * 8) = o;
  }
}

// --------------------------- flat-B GEMM ------------------------------------
// C = A @ B + bias [,gelu].  A: [M][K] bf16 via LDS (gload_lds + XOR swizzle),
// B: frag-packed bf16 loaded straight to VGPRs (no LDS, single-buffered).
// BN=256 fixed, 8 waves 2M x 4N; per-wave (BM/2) x 64, NR=4.

template<int BM>
__device__ __forceinline__ void stage_A(
    const unsigned short* __restrict__ Ab, int K, int kb,
    short* __restrict__ dst, int tid) {
#pragma unroll
  for (int j = 0; j < BM / 64; ++j) {
    const int ci = j * 512 + tid;
    const int row = ci >> 3;
    const int gc = (ci & 7) ^ (row & 7);
    gload_lds16(Ab + (size_t)row * K + kb + gc * 8, dst + ci * 8);
  }
}

template<int BM, bool GELU, typename OUT_T>
__global__ __launch_bounds__(512, 2) void gemm_flat(
    const unsigned short* __restrict__ A,
    const unsigned short* __restrict__ Bp,   // frag-packed
    const float* __restrict__ x_op,
    const float* __restrict__ bias_base,     // [8][2][N]
    int expert, OUT_T* __restrict__ Cout, int M, int N, int K)
{
  constexpr int BN = 256, NR = 4;
  constexpr int MR = BM / 32;             // 16-row frags per wave (8 or 4)
  constexpr int SA = BM / 64;             // A stage instrs per K-tile (4 or 2)
  constexpr int BUF = BM * 64;            // shorts per A double-buffer half
  __shared__ short smem[2 * BUF];

  const int tid  = threadIdx.x;
  const int wid  = tid >> 6, lane = tid & 63;
  const int wm   = wid >> 2, wn = wid & 3;
  const int lq   = lane >> 4, lr = lane & 15;

  // XCD-aware bijective swizzle (nwg % 8 == 0), bn-slow: the small B panel
  // (<=1-2MB per XCD chunk) stays L2-resident; A streams via DMA.
  const int nwg = gridDim.x;
  const int id  = blockIdx.x;
  const int s   = (id & 7) * (nwg >> 3) + (id >> 3);
  const int nbm = M / BM;
  const int bn  = s / nbm, bm = s % nbm;

  const unsigned short* Ab = A + (size_t)bm * BM * K;
  const short8* Bq = (const short8*)Bp;
  const int nf0 = bn * (BN / 16) + wn * NR;
  const int nf_stride = N >> 4;

  f32x4 acc[MR][NR] = {};
  short8 breg[NR][2];

  // prologue: A(0) staged into buffer 0
  stage_A<BM>(Ab, K, 0, smem, tid);

  const int nkt = K / 64;
  for (int t = 0; t < nkt; ++t) {
    const char* cA = (const char*)(smem + (t & 1) * BUF);
    short* nxt = smem + ((t + 1) & 1) * BUF;

    // B(t) -> regs (plain loads; compiler inserts its own counted wait
    // before first MFMA use). L2-hit latency covered by wait+barrier+lead-in.
#pragma unroll
    for (int n = 0; n < NR; ++n)
#pragma unroll
      for (int ks = 0; ks < 2; ++ks)
        breg[n][ks] = Bq[((size_t)(t * nf_stride + nf0 + n) * 2 + ks) * 64 + lane];

    // A(t+1) DMA, then counted wait draining exactly A(t) (oldest SA ops);
    // B(t) + A(t+1) stay in flight across the barrier (T4).
    if (t + 1 < nkt) { stage_A<BM>(Ab, K, (t + 1) * 64, nxt, tid); wait_vm<8 + SA>(); }
    else             { wait_vm<8>(); }
    SBAR;

    // tile body: compiler-scheduled (R7 lesson: no intra-tile sync/pins)
#pragma unroll
    for (int ks = 0; ks < 2; ++ks)
#pragma unroll
      for (int mh = 0; mh < 2; ++mh) {
        short8 af[MR / 2];
#pragma unroll
        for (int mm = 0; mm < MR / 2; ++mm) {
          const int ra = wm * (BM / 2) + (mh * (MR / 2) + mm) * 16 + lr;
          const int ch = ((ks << 2) | lq) ^ (ra & 7);
          af[mm] = *(const short8*)(cA + ra * 128 + ch * 16);
        }
#pragma unroll
        for (int mm = 0; mm < MR / 2; ++mm)
#pragma unroll
          for (int n = 0; n < NR; ++n)
            acc[mh * (MR / 2) + mm][n] = __builtin_amdgcn_mfma_f32_16x16x32_bf16(
                af[mm], breg[n][ks], acc[mh * (MR / 2) + mm][n], 0, 0, 0);
      }

    LGKM0;   // my ds_reads of cA done -> next tile's DMA may overwrite it
    SBAR;
  }

  // Epilogue: C/D layout col=lane&15, row=(lane>>4)*4+reg [m89-verified]
  const int op = compute_op(x_op);
  const float* bias = bias_base + ((size_t)op * 2 + (size_t)expert) * (size_t)N;
#pragma unroll
  for (int f = 0; f < MR; ++f) {
    const int grow0 = bm * BM + wm * (BM / 2) + f * 16 + lq * 4;
#pragma unroll
    for (int n = 0; n < NR; ++n) {
      const int gcol = bn * BN + wn * 64 + n * 16 + lr;
      const float bv = bias[gcol];
#pragma unroll
      for (int r = 0; r < 4; ++r) {
        float v = acc[f][n][r] + bv;
        if constexpr (GELU) v = gelu_tanh(v);
        const size_t off = (size_t)(grow0 + r) * N + gcol;
        if constexpr (std::is_same<OUT_T, float>::value) Cout[off] = v;
        else Cout[off] = f2bf(v);
      }
    }
  }
}

// --------------------------- launcher ---------------------------------------
extern "C" void kernel_launch(void* const* d_in, const int* in_sizes, int n_in,
                              void* d_out, int out_size, void* d_ws, size_t ws_size,
                              hipStream_t stream) {
  const float* x  = (const float*)d_in[0];
  const float* W1 = (const float*)d_in[1];   // [8][2][1024][4096]
  const float* b1 = (const float*)d_in[2];   // [8][2][4096]
  const float* W2 = (const float*)d_in[3];   // [8][2][4096][1024]
  const float* b2 = (const float*)d_in[4];   // [8][2][1024]
  float* out = (float*)d_out;

  const int D = 1024, F = 4096, M = 8192;    // M = B*S = 4*2048

  // ws layout: [xb 16.8MB][w1p 16.8MB][w2p 16.8MB][h 67.1MB]
  char* ws = (char*)d_ws;
  unsigned short* xb  = (unsigned short*)ws;
  unsigned short* w1p = (unsigned short*)(ws + (size_t)M * D * 2);
  unsigned short* w2p = (unsigned short*)(ws + (size_t)M * D * 2 + (size_t)2 * D * F * 2);
  unsigned short* h   = (unsigned short*)(ws + (size_t)M * D * 2 + (size_t)4 * D * F * 2);
  unsigned short* x1b = (unsigned short*)d_out;  // stage-0 output parked in d_out

  prep_kernel<<<4096 + 4 * 1024, 256, 0, stream>>>(x, W1, W2, xb, w1p, w2p);

  // GEMM1: M=8192,N=4096,K=1024  BM=256, grid 512, bn-slow
  // GEMM2: M=8192,N=1024,K=4096  BM=128, grid 256, bn-slow
  // expert 0
  gemm_flat<256, true,  unsigned short><<<(M/256)*(F/256), 512, 0, stream>>>(xb,  w1p,                 x, b1, 0, h,   M, F, D);
  gemm_flat<128, false, unsigned short><<<(M/128)*(D/256), 512, 0, stream>>>(h,   w2p,                 x, b2, 0, x1b, M, D, F);
  // expert 1
  gemm_flat<256, true,  unsigned short><<<(M/256)*(F/256), 512, 0, stream>>>(x1b, w1p + (size_t)F * D, x, b1, 1, h,   M, F, D);
  gemm_flat<128, false, float         ><<<(M/128)*(D/256), 512, 0, stream>>>(h,   w2p + (size_t)D * F, x, b2, 1, out, M, D, F);
}

// Round 10
// 374.026 us; speedup vs baseline: 1.2665x; 1.0860x over previous
//
#include <hip/hip_runtime.h>
#include <hip/hip_bf16.h>
#include <stdint.h>
#include <type_traits>

// ---------------------------------------------------------------------------
// MultiExpertMoELayer: opcode-routed 2-stage FFN chain.
//   op = argmax(x[0,0,0:8]);  for e in 0..1: x = gelu(x@W1[op,e]+b1)@W2[op,e]+b2
// Round 10 (base = R7 loose-sync LDS-B, 338us best):
//   R9 flat-B refuted (L2 per-CU BW 56B/cyc < LDS 128B/cyc). Back to LDS-B.
//   1. GEMM2: BM=128/BN=128, LDS 64KB, launch_bounds(512,4) -> VGPR<=128,
//      TWO blocks/CU: cross-block overlap breaks the 8-wave barrier lockstep
//      (mechanism of m97's 912TF@3blocks). acc=32 regs, fits easily.
//   2. GEMM1: 32x32x16 MFMA in the loose body (R5's failure was spill +
//      vmcnt(0) drain, not the MFMA): same LDS bytes, +17% MFMA pipe rate,
//      half the issue slots. Register audit: acc128+af4+bf8+addr~40 ~ 180.
//   3. Keep: full-tile staging at top, counted vmcnt(S) (T4), single
//      lgkmcnt(0)+barrier pair per tile, no intra-tile pins (R7 lesson).
// Canary: absmax must stay exactly 0.01171875 (R5 proved 32x32 preserves it).
// ---------------------------------------------------------------------------

typedef __attribute__((ext_vector_type(8))) short short8;    // 8 x bf16
typedef __attribute__((ext_vector_type(4))) float f32x4;     // 16x16 accum
typedef __attribute__((ext_vector_type(16))) float f32x16;   // 32x32 accum

#define LGKM0  asm volatile("s_waitcnt lgkmcnt(0)" ::: "memory")
#define SBAR   __builtin_amdgcn_s_barrier()

template<int VM> __device__ __forceinline__ void wait_vm() {
  if constexpr (VM == 8)      asm volatile("s_waitcnt vmcnt(8)" ::: "memory");
  else if constexpr (VM == 4) asm volatile("s_waitcnt vmcnt(4)" ::: "memory");
  else                        asm volatile("s_waitcnt vmcnt(0)" ::: "memory");
}

__device__ __forceinline__ unsigned short f2bf(float f) {
  union { float f; uint32_t u; } v; v.f = f;
  return (unsigned short)((v.u + 0x7fffu + ((v.u >> 16) & 1u)) >> 16);  // RNE
}

// jax.nn.gelu(approximate=True): 0.5x(1+tanh(sqrt(2/pi)(x+0.044715x^3)))
__device__ __forceinline__ float gelu_tanh(float x) {
  float u = 0.7978845608028654f * (x + 0.044715f * x * x * x);
  float e = __expf(2.0f * u);
  float t = 1.0f - 2.0f / (e + 1.0f);   // tanh(u), safe at +/-inf
  return 0.5f * x * (1.0f + t);
}

__device__ __forceinline__ void gload_lds16(const void* g, void* l) {
  __builtin_amdgcn_global_load_lds(
      (const __attribute__((address_space(1))) void*)g,
      (__attribute__((address_space(3))) void*)l, 16, 0, 0);
}

// op = argmax(x[0,0,0:8]), first-max wins (matches jnp.argmax).
__device__ __forceinline__ int compute_op(const float* __restrict__ x) {
  int best = 0; float bv = x[0];
#pragma unroll
  for (int i = 1; i < 8; ++i) { float v = x[i]; if (v > bv) { bv = v; best = i; } }
  return best;
}

// --------------------------- fused prep kernel ------------------------------
// blocks [0, 4096)   : x fp32 -> bf16 (8 elems/thread)
// blocks [4096, 8192): 4 transpose+cvt jobs of 1024 blocks each
//   job 0/1: W1[op,e] [1024][4096] -> w1t[e] [4096][1024]
//   job 2/3: W2[op,e] [4096][1024] -> w2t[e] [1024][4096]
__global__ __launch_bounds__(256) void prep_kernel(
    const float* __restrict__ x, const float* __restrict__ W1,
    const float* __restrict__ W2,
    unsigned short* __restrict__ xb, unsigned short* __restrict__ w1t,
    unsigned short* __restrict__ w2t) {
  __shared__ float tile[64][65];
  const int bid = blockIdx.x;
  const int t = threadIdx.x;
  if (bid < 4096) {
    const int i = bid * 256 + t;
    const float4* xv = (const float4*)x;
    float4 v0 = xv[i * 2], v1 = xv[i * 2 + 1];
    ushort4 o0, o1;
    o0.x = f2bf(v0.x); o0.y = f2bf(v0.y); o0.z = f2bf(v0.z); o0.w = f2bf(v0.w);
    o1.x = f2bf(v1.x); o1.y = f2bf(v1.y); o1.z = f2bf(v1.z); o1.w = f2bf(v1.w);
    ((ushort4*)xb)[i * 2] = o0; ((ushort4*)xb)[i * 2 + 1] = o1;
    return;
  }
  const int op = compute_op(x);
  const int j = bid - 4096;
  const int job = j >> 10, w = j & 1023;
  const int e = job & 1;
  const bool isW1 = (job < 2);
  const int R = isW1 ? 1024 : 4096;
  const int C = isW1 ? 4096 : 1024;
  const float* W = (isW1 ? W1 : W2) + ((size_t)op * 2 + (size_t)e) * (size_t)R * C;
  unsigned short* dst0 = (isW1 ? w1t : w2t) + (size_t)e * 4096 * 1024;
  const int tc = w % (C >> 6), tr = w / (C >> 6);
  {
    const int r  = t >> 2;
    const int c0 = (t & 3) * 16;
    const float* src = W + (size_t)(tr * 64 + r) * C + tc * 64 + c0;
#pragma unroll
    for (int jj = 0; jj < 16; jj += 4) {
      float4 v = *(const float4*)(src + jj);
      tile[r][c0 + jj]     = v.x;
      tile[r][c0 + jj + 1] = v.y;
      tile[r][c0 + jj + 2] = v.z;
      tile[r][c0 + jj + 3] = v.w;
    }
  }
  __syncthreads();
  {
    const int c  = t >> 2;
    const int r0 = (t & 3) * 16;
    unsigned short* dp = dst0 + (size_t)(tc * 64 + c) * R + tr * 64 + r0;
#pragma unroll
    for (int jj = 0; jj < 16; jj += 4) {
      ushort4 o;
      o.x = f2bf(tile[r0 + jj][c]);
      o.y = f2bf(tile[r0 + jj + 1][c]);
      o.z = f2bf(tile[r0 + jj + 2][c]);
      o.w = f2bf(tile[r0 + jj + 3][c]);
      *(ushort4*)(dp + jj) = o;
    }
  }
}

// --------------------------- shared staging ---------------------------------
// LDS per buffer: A [BM][64] + B [BN][64] bf16; 16B chunk c of row r stored
// at c ^ (r&7) (both-sides swizzle with pre-swizzled staging source).
template<int BM, int BN>
__device__ __forceinline__ void stage_tile_all(
    const unsigned short* __restrict__ Ab,
    const unsigned short* __restrict__ Bb,
    int K, int kb, short* __restrict__ dst, int tid) {
  constexpr int SA = BM / 64, SB = BN / 64, ABK = BM * 64;
#pragma unroll
  for (int j = 0; j < SA; ++j) {
    const int ci = j * 512 + tid;
    const int row = ci >> 3;
    const int gc = (ci & 7) ^ (row & 7);
    gload_lds16(Ab + (size_t)row * K + kb + gc * 8, dst + ci * 8);
  }
#pragma unroll
  for (int j = 0; j < SB; ++j) {
    const int cj = j * 512 + tid;
    const int row = cj >> 3;
    const int gc = (cj & 7) ^ (row & 7);
    gload_lds16(Bb + (size_t)row * K + kb + gc * 8, dst + ABK + cj * 8);
  }
}

// --------------------------- GEMM1: 256x256, 32x32x16, loose ----------------
// 8 waves 2M x 4N; per-wave 128x64 = 4x2 frags of 32x32. 1 block/CU (128KB).
template<bool GELU, typename OUT_T>
__global__ __launch_bounds__(512, 2) void gemm1_32(
    const unsigned short* __restrict__ A,
    const unsigned short* __restrict__ Bt,
    const float* __restrict__ x_op,
    const float* __restrict__ bias_base,     // [8][2][N]
    int expert, OUT_T* __restrict__ Cout, int M, int N, int K)
{
  constexpr int BM = 256, BN = 256, BK = 64;
  constexpr int BUF = (BM + BN) * BK;
  __shared__ short smem[2 * BUF];

  const int tid  = threadIdx.x;
  const int wid  = tid >> 6, lane = tid & 63;
  const int wm   = wid >> 2, wn = wid & 3;
  const int l31  = lane & 31, lh = lane >> 5;

  // XCD swizzle, bm-slow (R7 config)
  const int nwg = gridDim.x;
  const int id  = blockIdx.x;
  const int s   = (id & 7) * (nwg >> 3) + (id >> 3);
  const int nbn = N / BN;
  const int bm  = s / nbn, bn = s % nbn;

  const unsigned short* Ab = A  + (size_t)bm * BM * K;
  const unsigned short* Bb = Bt + (size_t)bn * BN * K;

  f32x16 acc[4][2] = {};

  stage_tile_all<BM, BN>(Ab, Bb, K, 0, smem, tid);

  const int nkt = K / BK;
  for (int t = 0; t < nkt; ++t) {
    const char* cA = (const char*)(smem + (t & 1) * BUF);
    const char* cB = cA + BM * BK * 2;
    short* nxt = smem + ((t + 1) & 1) * BUF;

    if (t + 1 < nkt) { stage_tile_all<BM, BN>(Ab, Bb, K, (t + 1) * BK, nxt, tid); wait_vm<8>(); }
    else             { wait_vm<0>(); }
    SBAR;

    // loose body: 4 k-slices of 16; compiler schedules reads vs MFMAs
#pragma unroll
    for (int ks = 0; ks < 4; ++ks) {
      short8 bf[2];
#pragma unroll
      for (int nf = 0; nf < 2; ++nf) {
        const int rb = wn * 64 + nf * 32 + l31;
        const int ch = (ks * 2 + lh) ^ (rb & 7);
        bf[nf] = *(const short8*)(cB + rb * 128 + ch * 16);
      }
#pragma unroll
      for (int mf = 0; mf < 4; ++mf) {
        const int ra = wm * 128 + mf * 32 + l31;
        const int ch = (ks * 2 + lh) ^ (ra & 7);
        const short8 af = *(const short8*)(cA + ra * 128 + ch * 16);
#pragma unroll
        for (int nf = 0; nf < 2; ++nf)
          acc[mf][nf] = __builtin_amdgcn_mfma_f32_32x32x16_bf16(
              af, bf[nf], acc[mf][nf], 0, 0, 0);
      }
    }

    LGKM0;   // my ds_reads of cur done -> next tile's DMA may overwrite it
    SBAR;
  }

  // Epilogue: 32x32 C/D: col=lane&31, row=(r&3)+8*(r>>2)+4*(lane>>5) [m74/m101]
  const int op = compute_op(x_op);
  const float* bias = bias_base + ((size_t)op * 2 + (size_t)expert) * (size_t)N;
#pragma unroll
  for (int mf = 0; mf < 4; ++mf) {
    const int grow_base = bm * BM + wm * 128 + mf * 32 + 4 * lh;
#pragma unroll
    for (int nf = 0; nf < 2; ++nf) {
      const int gcol = bn * BN + wn * 64 + nf * 32 + l31;
      const float bv = bias[gcol];
#pragma unroll
      for (int r = 0; r < 16; ++r) {
        const int grow = grow_base + (r & 3) + 8 * (r >> 2);
        float v = acc[mf][nf][r] + bv;
        if constexpr (GELU) v = gelu_tanh(v);
        const size_t off = (size_t)grow * N + gcol;
        if constexpr (std::is_same<OUT_T, float>::value) Cout[off] = v;
        else Cout[off] = f2bf(v);
      }
    }
  }
}

// --------------------------- GEMM2: 128x128, 16x16x32, 2 blocks/CU ----------
// 8 waves 2M x 4N; per-wave 64x32 = 4x2 frags of 16x16. LDS 64KB, VGPR<=128.
template<bool GELU, typename OUT_T>
__global__ __launch_bounds__(512, 4) void gemm2_16(
    const unsigned short* __restrict__ A,
    const unsigned short* __restrict__ Bt,
    const float* __restrict__ x_op,
    const float* __restrict__ bias_base,     // [8][2][N]
    int expert, OUT_T* __restrict__ Cout, int M, int N, int K)
{
  constexpr int BM = 128, BN = 128, BK = 64;
  constexpr int BUF = (BM + BN) * BK;
  __shared__ short smem[2 * BUF];

  const int tid  = threadIdx.x;
  const int wid  = tid >> 6, lane = tid & 63;
  const int wm   = wid >> 2, wn = wid & 3;
  const int lq   = lane >> 4, lr = lane & 15;

  // XCD swizzle, bn-slow: 1MB B-panel L2-resident per XCD chunk
  const int nwg = gridDim.x;
  const int id  = blockIdx.x;
  const int s   = (id & 7) * (nwg >> 3) + (id >> 3);
  const int nbm = M / BM;
  const int bn  = s / nbm, bm = s % nbm;

  const unsigned short* Ab = A  + (size_t)bm * BM * K;
  const unsigned short* Bb = Bt + (size_t)bn * BN * K;

  f32x4 acc[4][2] = {};

  stage_tile_all<BM, BN>(Ab, Bb, K, 0, smem, tid);

  const int nkt = K / BK;
  for (int t = 0; t < nkt; ++t) {
    const char* cA = (const char*)(smem + (t & 1) * BUF);
    const char* cB = cA + BM * BK * 2;
    short* nxt = smem + ((t + 1) & 1) * BUF;

    if (t + 1 < nkt) { stage_tile_all<BM, BN>(Ab, Bb, K, (t + 1) * BK, nxt, tid); wait_vm<4>(); }
    else             { wait_vm<0>(); }
    SBAR;

#pragma unroll
    for (int ks = 0; ks < 2; ++ks) {
      short8 bf[2];
#pragma unroll
      for (int n = 0; n < 2; ++n) {
        const int rb = wn * 32 + n * 16 + lr;
        const int ch = ((ks << 2) | lq) ^ (rb & 7);
        bf[n] = *(const short8*)(cB + rb * 128 + ch * 16);
      }
#pragma unroll
      for (int mm = 0; mm < 4; ++mm) {
        const int ra = wm * 64 + mm * 16 + lr;
        const int ch = ((ks << 2) | lq) ^ (ra & 7);
        const short8 af = *(const short8*)(cA + ra * 128 + ch * 16);
#pragma unroll
        for (int n = 0; n < 2; ++n)
          acc[mm][n] = __builtin_amdgcn_mfma_f32_16x16x32_bf16(
              af, bf[n], acc[mm][n], 0, 0, 0);
      }
    }

    LGKM0;
    SBAR;
  }

  // Epilogue: 16x16 C/D: col=lane&15, row=(lane>>4)*4+reg [m89-verified]
  const int op = compute_op(x_op);
  const float* bias = bias_base + ((size_t)op * 2 + (size_t)expert) * (size_t)N;
#pragma unroll
  for (int f = 0; f < 4; ++f) {
    const int grow0 = bm * BM + wm * 64 + f * 16 + lq * 4;
#pragma unroll
    for (int n = 0; n < 2; ++n) {
      const int gcol = bn * BN + wn * 32 + n * 16 + lr;
      const float bv = bias[gcol];
#pragma unroll
      for (int r = 0; r < 4; ++r) {
        float v = acc[f][n][r] + bv;
        if constexpr (GELU) v = gelu_tanh(v);
        const size_t off = (size_t)(grow0 + r) * N + gcol;
        if constexpr (std::is_same<OUT_T, float>::value) Cout[off] = v;
        else Cout[off] = f2bf(v);
      }
    }
  }
}

// --------------------------- launcher ---------------------------------------
extern "C" void kernel_launch(void* const* d_in, const int* in_sizes, int n_in,
                              void* d_out, int out_size, void* d_ws, size_t ws_size,
                              hipStream_t stream) {
  const float* x  = (const float*)d_in[0];
  const float* W1 = (const float*)d_in[1];   // [8][2][1024][4096]
  const float* b1 = (const float*)d_in[2];   // [8][2][4096]
  const float* W2 = (const float*)d_in[3];   // [8][2][4096][1024]
  const float* b2 = (const float*)d_in[4];   // [8][2][1024]
  float* out = (float*)d_out;

  const int D = 1024, F = 4096, M = 8192;    // M = B*S = 4*2048

  // ws layout: [xb 16.8MB][w1t 16.8MB][w2t 16.8MB][h 67.1MB]
  char* ws = (char*)d_ws;
  unsigned short* xb  = (unsigned short*)ws;
  unsigned short* w1t = (unsigned short*)(ws + (size_t)M * D * 2);
  unsigned short* w2t = (unsigned short*)(ws + (size_t)M * D * 2 + (size_t)2 * D * F * 2);
  unsigned short* h   = (unsigned short*)(ws + (size_t)M * D * 2 + (size_t)4 * D * F * 2);
  unsigned short* x1b = (unsigned short*)d_out;  // stage-0 output parked in d_out

  prep_kernel<<<4096 + 4 * 1024, 256, 0, stream>>>(x, W1, W2, xb, w1t, w2t);

  // GEMM1: M=8192,N=4096,K=1024  BM=256,BN=256, grid 512, 1 block/CU
  // GEMM2: M=8192,N=1024,K=4096  BM=128,BN=128, grid 512, 2 blocks/CU
  // expert 0
  gemm1_32<true,  unsigned short><<<(M/256)*(F/256), 512, 0, stream>>>(xb,  w1t,                 x, b1, 0, h,   M, F, D);
  gemm2_16<false, unsigned short><<<(M/128)*(D/128), 512, 0, stream>>>(h,   w2t,                 x, b2, 0, x1b, M, D, F);
  // expert 1
  gemm1_32<true,  unsigned short><<<(M/256)*(F/256), 512, 0, stream>>>(x1b, w1t + (size_t)F * D, x, b1, 1, h,   M, F, D);
  gemm2_16<false, float         ><<<(M/128)*(D/128), 512, 0, stream>>>(h,   w2t + (size_t)D * F, x, b2, 1, out, M, D, F);
}

// Round 11
// 342.911 us; speedup vs baseline: 1.3814x; 1.0907x over previous
//
#include <hip/hip_runtime.h>
#include <hip/hip_bf16.h>
#include <stdint.h>
#include <type_traits>

// ---------------------------------------------------------------------------
// MultiExpertMoELayer: opcode-routed 2-stage FFN chain.
//   op = argmax(x[0,0,0:8]);  for e in 0..1: x = gelu(x@W1[op,e]+b1)@W2[op,e]+b2
// Round 11 (base = R7, 338us best; R10's two changes reverted):
//   GEMM1 -> faithful m201-style 4-phase/tile schedule (single change):
//     phase (ks,mh) = { stage 1 pair of tile t+1 ; counted vmcnt(4) at p0/p1
//     only ; SBAR ; ds_reads (reads AFTER publish barrier -- fixes R3's
//     read-before-wait defect) ; setprio(1) 16 MFMA setprio(0) ; SBAR }.
//     Stage order B0B1|B2B3|A0A2|A1A3 gives every pair 2-4 phases (~1300cyc)
//     of latency cover; vmcnt never drains mid-loop (T4). NO sched_barrier
//     (m141: order-pinning poison -- R3's other defect).
//   GEMM2: R7 loose structure unchanged (128x256, bn-slow).
// Canary: absmax must stay exactly 0.01171875 (accumulation DAG unchanged).
// ---------------------------------------------------------------------------

typedef __attribute__((ext_vector_type(8))) short short8;   // 8 x bf16 (4 VGPR)
typedef __attribute__((ext_vector_type(4))) float f32x4;    // MFMA accum

#define LGKM0  asm volatile("s_waitcnt lgkmcnt(0)" ::: "memory")
#define SBAR   __builtin_amdgcn_s_barrier()

template<int VM> __device__ __forceinline__ void wait_vm() {
  if constexpr (VM == 8)      asm volatile("s_waitcnt vmcnt(8)" ::: "memory");
  else if constexpr (VM == 6) asm volatile("s_waitcnt vmcnt(6)" ::: "memory");
  else if constexpr (VM == 4) asm volatile("s_waitcnt vmcnt(4)" ::: "memory");
  else if constexpr (VM == 2) asm volatile("s_waitcnt vmcnt(2)" ::: "memory");
  else                        asm volatile("s_waitcnt vmcnt(0)" ::: "memory");
}

__device__ __forceinline__ unsigned short f2bf(float f) {
  union { float f; uint32_t u; } v; v.f = f;
  return (unsigned short)((v.u + 0x7fffu + ((v.u >> 16) & 1u)) >> 16);  // RNE
}

// jax.nn.gelu(approximate=True): 0.5x(1+tanh(sqrt(2/pi)(x+0.044715x^3)))
__device__ __forceinline__ float gelu_tanh(float x) {
  float u = 0.7978845608028654f * (x + 0.044715f * x * x * x);
  float e = __expf(2.0f * u);
  float t = 1.0f - 2.0f / (e + 1.0f);   // tanh(u), safe at +/-inf
  return 0.5f * x * (1.0f + t);
}

__device__ __forceinline__ void gload_lds16(const void* g, void* l) {
  __builtin_amdgcn_global_load_lds(
      (const __attribute__((address_space(1))) void*)g,
      (__attribute__((address_space(3))) void*)l, 16, 0, 0);
}

// op = argmax(x[0,0,0:8]), first-max wins (matches jnp.argmax).
__device__ __forceinline__ int compute_op(const float* __restrict__ x) {
  int best = 0; float bv = x[0];
#pragma unroll
  for (int i = 1; i < 8; ++i) { float v = x[i]; if (v > bv) { bv = v; best = i; } }
  return best;
}

// --------------------------- fused prep kernel ------------------------------
// blocks [0, 4096)   : x fp32 -> bf16 (8 elems/thread)
// blocks [4096, 8192): 4 transpose+cvt jobs of 1024 blocks each
__global__ __launch_bounds__(256) void prep_kernel(
    const float* __restrict__ x, const float* __restrict__ W1,
    const float* __restrict__ W2,
    unsigned short* __restrict__ xb, unsigned short* __restrict__ w1t,
    unsigned short* __restrict__ w2t) {
  __shared__ float tile[64][65];
  const int bid = blockIdx.x;
  const int t = threadIdx.x;
  if (bid < 4096) {
    const int i = bid * 256 + t;
    const float4* xv = (const float4*)x;
    float4 v0 = xv[i * 2], v1 = xv[i * 2 + 1];
    ushort4 o0, o1;
    o0.x = f2bf(v0.x); o0.y = f2bf(v0.y); o0.z = f2bf(v0.z); o0.w = f2bf(v0.w);
    o1.x = f2bf(v1.x); o1.y = f2bf(v1.y); o1.z = f2bf(v1.z); o1.w = f2bf(v1.w);
    ((ushort4*)xb)[i * 2] = o0; ((ushort4*)xb)[i * 2 + 1] = o1;
    return;
  }
  const int op = compute_op(x);
  const int j = bid - 4096;
  const int job = j >> 10, w = j & 1023;
  const int e = job & 1;
  const bool isW1 = (job < 2);
  const int R = isW1 ? 1024 : 4096;
  const int C = isW1 ? 4096 : 1024;
  const float* W = (isW1 ? W1 : W2) + ((size_t)op * 2 + (size_t)e) * (size_t)R * C;
  unsigned short* dst0 = (isW1 ? w1t : w2t) + (size_t)e * 4096 * 1024;
  const int tc = w % (C >> 6), tr = w / (C >> 6);
  {
    const int r  = t >> 2;
    const int c0 = (t & 3) * 16;
    const float* src = W + (size_t)(tr * 64 + r) * C + tc * 64 + c0;
#pragma unroll
    for (int jj = 0; jj < 16; jj += 4) {
      float4 v = *(const float4*)(src + jj);
      tile[r][c0 + jj]     = v.x;
      tile[r][c0 + jj + 1] = v.y;
      tile[r][c0 + jj + 2] = v.z;
      tile[r][c0 + jj + 3] = v.w;
    }
  }
  __syncthreads();
  {
    const int c  = t >> 2;
    const int r0 = (t & 3) * 16;
    unsigned short* dp = dst0 + (size_t)(tc * 64 + c) * R + tr * 64 + r0;
#pragma unroll
    for (int jj = 0; jj < 16; jj += 4) {
      ushort4 o;
      o.x = f2bf(tile[r0 + jj][c]);
      o.y = f2bf(tile[r0 + jj + 1][c]);
      o.z = f2bf(tile[r0 + jj + 2][c]);
      o.w = f2bf(tile[r0 + jj + 3][c]);
      *(ushort4*)(dp + jj) = o;
    }
  }
}

// --------------------------- GEMM1: 256x256, 4-phase lockstep ---------------
// A: [M][K] bf16, Bt: [N][K] bf16. 8 waves 2M x 4N; per-wave 128x64.
// LDS buffer: A [256][64] then B [256][64]; 16B chunk c of row r at c^(r&7).
// A-load ja covers rows ja*64..+63; B-load jb likewise.

__device__ __forceinline__ void g1_stageA(
    int ja, const unsigned short* __restrict__ Ab, int K, int kb,
    short* __restrict__ dst, int tid) {
  const int ci = ja * 512 + tid;
  const int row = ci >> 3;
  const int gc = (ci & 7) ^ (row & 7);
  gload_lds16(Ab + (size_t)row * K + kb + gc * 8, dst + ci * 8);
}
__device__ __forceinline__ void g1_stageB(
    int jb, const unsigned short* __restrict__ Bb, int K, int kb,
    short* __restrict__ dst, int tid) {
  const int cj = jb * 512 + tid;
  const int row = cj >> 3;
  const int gc = (cj & 7) ^ (row & 7);
  gload_lds16(Bb + (size_t)row * K + kb + gc * 8, dst + 256 * 64 + cj * 8);
}

// phase (KS, MH): stage pair for t+1 -> counted wait (p0/p1) -> barrier ->
// reads -> setprio MFMA -> barrier.  bf persists from MH=0 into MH=1.
#define G1_PHASE(KS, MH, STAGE_STMT, WAIT_STMT)                               \
  {                                                                           \
    STAGE_STMT;                                                               \
    WAIT_STMT;                                                                \
    SBAR;                                                                     \
    if constexpr (MH == 0) {                                                  \
      _Pragma("unroll")                                                       \
      for (int n = 0; n < 4; ++n) {                                           \
        const int rb = wn * 64 + n * 16 + lr;                                 \
        const int ch = ((KS << 2) | lq) ^ (rb & 7);                           \
        bf[n] = *(const short8*)(cB + rb * 128 + ch * 16);                    \
      }                                                                       \
    }                                                                         \
    _Pragma("unroll")                                                         \
    for (int mm = 0; mm < 4; ++mm) {                                          \
      const int ra = wm * 128 + MH * 64 + mm * 16 + lr;                       \
      const int ch = ((KS << 2) | lq) ^ (ra & 7);                             \
      af[mm] = *(const short8*)(cA + ra * 128 + ch * 16);                     \
    }                                                                         \
    __builtin_amdgcn_s_setprio(1);                                            \
    _Pragma("unroll")                                                         \
    for (int mm = 0; mm < 4; ++mm)                                            \
      _Pragma("unroll")                                                       \
      for (int n = 0; n < 4; ++n)                                             \
        acc[MH * 4 + mm][n] = __builtin_amdgcn_mfma_f32_16x16x32_bf16(        \
            af[mm], bf[n], acc[MH * 4 + mm][n], 0, 0, 0);                     \
    __builtin_amdgcn_s_setprio(0);                                            \
    SBAR;                                                                     \
  }

template<bool GELU, typename OUT_T>
__global__ __launch_bounds__(512, 2) void gemm1_4ph(
    const unsigned short* __restrict__ A,
    const unsigned short* __restrict__ Bt,
    const float* __restrict__ x_op,
    const float* __restrict__ bias_base,     // [8][2][N]
    int expert, OUT_T* __restrict__ Cout, int M, int N, int K)
{
  constexpr int BM = 256, BN = 256, BK = 64;
  constexpr int BUF = (BM + BN) * BK;       // 64 KB per buffer half
  __shared__ short smem[2 * BUF];

  const int tid  = threadIdx.x;
  const int wid  = tid >> 6, lane = tid & 63;
  const int wm   = wid >> 2, wn = wid & 3;
  const int lq   = lane >> 4, lr = lane & 15;

  // XCD swizzle, bm-slow (R7 config)
  const int nwg = gridDim.x;
  const int id  = blockIdx.x;
  const int s   = (id & 7) * (nwg >> 3) + (id >> 3);
  const int nbn = N / BN;
  const int bm  = s / nbn, bn = s % nbn;

  const unsigned short* Ab = A  + (size_t)bm * BM * K;
  const unsigned short* Bb = Bt + (size_t)bn * BN * K;

  const int op = compute_op(x_op);   // early: its 8 loads drain at first wait

  f32x4 acc[8][4] = {};

  // prologue: tile 0 in issue order B0 B1 B2 B3 A0 A2 A1 A3
  g1_stageB(0, Bb, K, 0, smem, tid); g1_stageB(1, Bb, K, 0, smem, tid);
  g1_stageB(2, Bb, K, 0, smem, tid); g1_stageB(3, Bb, K, 0, smem, tid);
  g1_stageA(0, Ab, K, 0, smem, tid); g1_stageA(2, Ab, K, 0, smem, tid);
  g1_stageA(1, Ab, K, 0, smem, tid); g1_stageA(3, Ab, K, 0, smem, tid);

  const int nkt = K / BK;
  for (int t = 0; t < nkt; ++t) {
    const char* cA = (const char*)(smem + (t & 1) * BUF);
    const char* cB = cA + BM * BK * 2;
    short* nxt = smem + ((t + 1) & 1) * BUF;
    const int kb = (t + 1) * BK;
    const bool pf = (t + 1) < nkt;

    short8 bf[4], af[4];
    // p0 (ks0,mh0): needs B(t)+A0A2(t); leaves A1A3(t)+B0B1(t+1) in flight
    G1_PHASE(0, 0,
      if (pf) { g1_stageB(0, Bb, K, kb, nxt, tid); g1_stageB(1, Bb, K, kb, nxt, tid); },
      if (pf) wait_vm<4>(); else wait_vm<2>());
    // p1 (ks0,mh1): needs A1A3(t); leaves B0..B3(t+1) in flight
    G1_PHASE(0, 1,
      if (pf) { g1_stageB(2, Bb, K, kb, nxt, tid); g1_stageB(3, Bb, K, kb, nxt, tid); },
      if (pf) wait_vm<4>(); else wait_vm<0>());
    // p2 (ks1,mh0): all t data landed; no wait
    G1_PHASE(1, 0,
      if (pf) { g1_stageA(0, Ab, K, kb, nxt, tid); g1_stageA(2, Ab, K, kb, nxt, tid); }, );
    // p3 (ks1,mh1)
    G1_PHASE(1, 1,
      if (pf) { g1_stageA(1, Ab, K, kb, nxt, tid); g1_stageA(3, Ab, K, kb, nxt, tid); }, );
  }

  // Epilogue: C/D layout col=lane&15, row=(lane>>4)*4+reg [m89-verified]
  const float* bias = bias_base + ((size_t)op * 2 + (size_t)expert) * (size_t)N;
#pragma unroll
  for (int f = 0; f < 8; ++f) {
    const int grow0 = bm * BM + wm * 128 + f * 16 + lq * 4;
#pragma unroll
    for (int n = 0; n < 4; ++n) {
      const int gcol = bn * BN + wn * 64 + n * 16 + lr;
      const float bv = bias[gcol];
#pragma unroll
      for (int r = 0; r < 4; ++r) {
        float v = acc[f][n][r] + bv;
        if constexpr (GELU) v = gelu_tanh(v);
        const size_t off = (size_t)(grow0 + r) * N + gcol;
        if constexpr (std::is_same<OUT_T, float>::value) Cout[off] = v;
        else Cout[off] = f2bf(v);
      }
    }
  }
}

// --------------------------- GEMM2: R7 loose (unchanged) --------------------
template<int BM, int BN>
__device__ __forceinline__ void stage_tile_all(
    const unsigned short* __restrict__ Ab,
    const unsigned short* __restrict__ Bb,
    int K, int kb, short* __restrict__ dst, int tid) {
  constexpr int SA = BM / 64, SB = BN / 64, ABK = BM * 64;
#pragma unroll
  for (int j = 0; j < SA; ++j) {
    const int ci = j * 512 + tid;
    const int row = ci >> 3;
    const int gc = (ci & 7) ^ (row & 7);
    gload_lds16(Ab + (size_t)row * K + kb + gc * 8, dst + ci * 8);
  }
#pragma unroll
  for (int j = 0; j < SB; ++j) {
    const int cj = j * 512 + tid;
    const int row = cj >> 3;
    const int gc = (cj & 7) ^ (row & 7);
    gload_lds16(Bb + (size_t)row * K + kb + gc * 8, dst + ABK + cj * 8);
  }
}

template<bool GELU, typename OUT_T>
__global__ __launch_bounds__(512, 2) void gemm2_loose(
    const unsigned short* __restrict__ A,
    const unsigned short* __restrict__ Bt,
    const float* __restrict__ x_op,
    const float* __restrict__ bias_base,     // [8][2][N]
    int expert, OUT_T* __restrict__ Cout, int M, int N, int K)
{
  constexpr int BM = 128, BN = 256, BK = 64;
  constexpr int MR = 4, NR = 4, S = BM / 64 + BN / 64;   // S = 6
  constexpr int BUF = (BM + BN) * BK;
  __shared__ short smem[2 * BUF];

  const int tid  = threadIdx.x;
  const int wid  = tid >> 6, lane = tid & 63;
  const int wm   = wid >> 2, wn = wid & 3;
  const int lq   = lane >> 4, lr = lane & 15;

  const int nwg = gridDim.x;
  const int id  = blockIdx.x;
  const int s   = (id & 7) * (nwg >> 3) + (id >> 3);
  const int nbm = M / BM;
  const int bn  = s / nbm, bm = s % nbm;   // bn-slow: B panel L2-resident

  const unsigned short* Ab = A  + (size_t)bm * BM * K;
  const unsigned short* Bb = Bt + (size_t)bn * BN * K;

  f32x4 acc[MR][NR] = {};

  stage_tile_all<BM, BN>(Ab, Bb, K, 0, smem, tid);

  const int nkt = K / BK;
  for (int t = 0; t < nkt; ++t) {
    const char* cA = (const char*)(smem + (t & 1) * BUF);
    const char* cB = cA + BM * BK * 2;
    short* nxt = smem + ((t + 1) & 1) * BUF;

    if (t + 1 < nkt) { stage_tile_all<BM, BN>(Ab, Bb, K, (t + 1) * BK, nxt, tid); wait_vm<S>(); }
    else             { wait_vm<0>(); }
    SBAR;

#pragma unroll
    for (int ks = 0; ks < 2; ++ks) {
      short8 bf[NR];
#pragma unroll
      for (int n = 0; n < NR; ++n) {
        const int rb = wn * 64 + n * 16 + lr;
        const int ch = ((ks << 2) | lq) ^ (rb & 7);
        bf[n] = *(const short8*)(cB + rb * 128 + ch * 16);
      }
#pragma unroll
      for (int mh = 0; mh < 2; ++mh) {
        short8 af[MR / 2];
#pragma unroll
        for (int mm = 0; mm < MR / 2; ++mm) {
          const int ra = wm * (BM / 2) + (mh * (MR / 2) + mm) * 16 + lr;
          const int ch = ((ks << 2) | lq) ^ (ra & 7);
          af[mm] = *(const short8*)(cA + ra * 128 + ch * 16);
        }
#pragma unroll
        for (int mm = 0; mm < MR / 2; ++mm)
#pragma unroll
          for (int n = 0; n < NR; ++n)
            acc[mh * (MR / 2) + mm][n] = __builtin_amdgcn_mfma_f32_16x16x32_bf16(
                af[mm], bf[n], acc[mh * (MR / 2) + mm][n], 0, 0, 0);
      }
    }

    LGKM0;
    SBAR;
  }

  const int op = compute_op(x_op);
  const float* bias = bias_base + ((size_t)op * 2 + (size_t)expert) * (size_t)N;
#pragma unroll
  for (int f = 0; f < MR; ++f) {
    const int grow0 = bm * BM + wm * (BM / 2) + f * 16 + lq * 4;
#pragma unroll
    for (int n = 0; n < NR; ++n) {
      const int gcol = bn * BN + wn * 64 + n * 16 + lr;
      const float bv = bias[gcol];
#pragma unroll
      for (int r = 0; r < 4; ++r) {
        float v = acc[f][n][r] + bv;
        if constexpr (GELU) v = gelu_tanh(v);
        const size_t off = (size_t)(grow0 + r) * N + gcol;
        if constexpr (std::is_same<OUT_T, float>::value) Cout[off] = v;
        else Cout[off] = f2bf(v);
      }
    }
  }
}

// --------------------------- launcher ---------------------------------------
extern "C" void kernel_launch(void* const* d_in, const int* in_sizes, int n_in,
                              void* d_out, int out_size, void* d_ws, size_t ws_size,
                              hipStream_t stream) {
  const float* x  = (const float*)d_in[0];
  const float* W1 = (const float*)d_in[1];   // [8][2][1024][4096]
  const float* b1 = (const float*)d_in[2];   // [8][2][4096]
  const float* W2 = (const float*)d_in[3];   // [8][2][4096][1024]
  const float* b2 = (const float*)d_in[4];   // [8][2][1024]
  float* out = (float*)d_out;

  const int D = 1024, F = 4096, M = 8192;    // M = B*S = 4*2048

  // ws layout: [xb 16.8MB][w1t 16.8MB][w2t 16.8MB][h 67.1MB]
  char* ws = (char*)d_ws;
  unsigned short* xb  = (unsigned short*)ws;
  unsigned short* w1t = (unsigned short*)(ws + (size_t)M * D * 2);
  unsigned short* w2t = (unsigned short*)(ws + (size_t)M * D * 2 + (size_t)2 * D * F * 2);
  unsigned short* h   = (unsigned short*)(ws + (size_t)M * D * 2 + (size_t)4 * D * F * 2);
  unsigned short* x1b = (unsigned short*)d_out;  // stage-0 output parked in d_out

  prep_kernel<<<4096 + 4 * 1024, 256, 0, stream>>>(x, W1, W2, xb, w1t, w2t);

  // GEMM1: M=8192,N=4096,K=1024  256x256 4-phase, grid 512
  // GEMM2: M=8192,N=1024,K=4096  128x256 loose,   grid 256
  // expert 0
  gemm1_4ph<true,  unsigned short><<<(M/256)*(F/256), 512, 0, stream>>>(xb,  w1t,                 x, b1, 0, h,   M, F, D);
  gemm2_loose<false, unsigned short><<<(M/128)*(D/256), 512, 0, stream>>>(h,   w2t,                 x, b2, 0, x1b, M, D, F);
  // expert 1
  gemm1_4ph<true,  unsigned short><<<(M/256)*(F/256), 512, 0, stream>>>(x1b, w1t + (size_t)F * D, x, b1, 1, h,   M, F, D);
  gemm2_loose<false, float         ><<<(M/128)*(D/256), 512, 0, stream>>>(h,   w2t + (size_t)D * F, x, b2, 1, out, M, D, F);
}